// Round 1
// baseline (1166.564 us; speedup 1.0000x reference)
//
#include <hip/hip_runtime.h>
#include <hip/hip_bf16.h>
#include <math.h>

// Problem constants (fixed by setup_inputs)
#define B_ 16
#define L_ 1024
#define E_ 512
#define H_ 8
#define DH 64

// ---------------- QueryScaler precompute ----------------
// qscale[d] = R_SOFTPLUS_0 * softplus(qs_scale[d]) * (1/sqrt(Dh))
__global__ void qscale_kernel(const float* __restrict__ qs_scale,
                              float* __restrict__ qscale) {
    int d = threadIdx.x;
    if (d < DH) {
        float x = qs_scale[d];
        float sp = (x > 20.f) ? x : log1pf(expf(x));
        qscale[d] = 1.442695041f * sp * 0.125f;
    }
}

// ---------------- Tiled fp32 GEMM: C = A(M,512) * W(N,512)^T + bias --------
// MODE 0: QKV projection -> scatter into Q/K/V (B*H, L, DH), scale Q by qscale
// MODE 1: out projection -> D0[r*E_ + f]
#define TM 128
#define TN 128
#define TK 16

template<int MODE>
__global__ __launch_bounds__(256) void gemm_fp32(
    const float* __restrict__ A, const float* __restrict__ W,
    const float* __restrict__ bias, const float* __restrict__ qscale,
    float* __restrict__ D0, float* __restrict__ D1, float* __restrict__ D2)
{
    __shared__ float As[TK][TM + 4];
    __shared__ float Bs[TK][TN + 4];
    const int tid = threadIdx.x;
    const int m0 = blockIdx.x * TM;
    const int n0 = blockIdx.y * TN;
    const int lr = tid >> 2;            // 0..63
    const int lc = (tid & 3) << 2;      // 0,4,8,12
    const int tr = (tid >> 4) << 3;     // 8-row slab
    const int tc = (tid & 15) << 3;     // 8-col slab
    float acc[8][8] = {};

    for (int k0 = 0; k0 < E_; k0 += TK) {
        #pragma unroll
        for (int hh = 0; hh < 2; hh++) {
            int r = lr + hh * 64;
            float4 av = *(const float4*)(A + (size_t)(m0 + r) * E_ + k0 + lc);
            As[lc + 0][r] = av.x; As[lc + 1][r] = av.y;
            As[lc + 2][r] = av.z; As[lc + 3][r] = av.w;
            float4 bv = *(const float4*)(W + (size_t)(n0 + r) * E_ + k0 + lc);
            Bs[lc + 0][r] = bv.x; Bs[lc + 1][r] = bv.y;
            Bs[lc + 2][r] = bv.z; Bs[lc + 3][r] = bv.w;
        }
        __syncthreads();
        #pragma unroll
        for (int kk = 0; kk < TK; kk++) {
            float4 a0 = *(const float4*)&As[kk][tr];
            float4 a1 = *(const float4*)&As[kk][tr + 4];
            float4 b0 = *(const float4*)&Bs[kk][tc];
            float4 b1 = *(const float4*)&Bs[kk][tc + 4];
            float a[8] = {a0.x, a0.y, a0.z, a0.w, a1.x, a1.y, a1.z, a1.w};
            float b[8] = {b0.x, b0.y, b0.z, b0.w, b1.x, b1.y, b1.z, b1.w};
            #pragma unroll
            for (int i = 0; i < 8; i++)
                #pragma unroll
                for (int j = 0; j < 8; j++)
                    acc[i][j] = fmaf(a[i], b[j], acc[i][j]);
        }
        __syncthreads();
    }

    #pragma unroll
    for (int i = 0; i < 8; i++) {
        int r = m0 + tr + i;
        #pragma unroll
        for (int j = 0; j < 8; j++) {
            int f = n0 + tc + j;
            float v = acc[i][j] + bias[f];
            if (MODE == 0) {
                int bb = r >> 10;           // r / L_
                int l = r & (L_ - 1);
                int part = f >> 9;          // 0:q 1:k 2:v
                int w = f & 511;
                int h = w >> 6, d = w & 63;
                size_t dst = (((size_t)(bb * H_ + h)) * L_ + l) * DH + d;
                if (part == 0)      D0[dst] = v * qscale[d];
                else if (part == 1) D1[dst] = v;
                else                D2[dst] = v;
            } else {
                D0[(size_t)r * E_ + f] = v;
            }
        }
    }
}

// ---------------- Flash-style fp32 attention ----------------
// One block = one (bh, 32-row Q tile). 256 threads = 32 rows x 8 lane-group.
// Q held in registers; K/V tiles staged in padded LDS; online softmax.
#define QB 32
#define KB 64
#define KPAD (DH + 4)

__global__ __launch_bounds__(256) void attn_kernel(
    const float* __restrict__ Q, const float* __restrict__ K,
    const float* __restrict__ V, const unsigned char* __restrict__ mask,
    float* __restrict__ O)
{
    const int qt = blockIdx.x;
    const int bh = blockIdx.y;
    const int b = bh >> 3;              // / H_
    const int h = bh & (H_ - 1);
    const float* Qp = Q + ((size_t)bh * L_ + qt * QB) * DH;
    const float* Kp = K + (size_t)bh * L_ * DH;
    const float* Vp = V + (size_t)bh * L_ * DH;
    const unsigned char* mp = mask + (size_t)b * L_;

    __shared__ float Ks[KB][KPAD];
    __shared__ float Vs[KB][KPAD];

    const int tid = threadIdx.x;
    const int row = tid >> 3;           // 0..31
    const int grp = tid & 7;            // 0..7

    // Q row in registers (16 float4 = 64 floats)
    float4 q[16];
    {
        const float4* qrow = (const float4*)(Qp + row * DH);
        #pragma unroll
        for (int i = 0; i < 16; i++) q[i] = qrow[i];
    }

    float m = -INFINITY, l = 0.f;
    float o[8] = {0.f, 0.f, 0.f, 0.f, 0.f, 0.f, 0.f, 0.f};

    for (int kt = 0; kt < L_; kt += KB) {
        __syncthreads();  // previous tile's Vs reads done before overwrite
        for (int i = tid * 4; i < KB * DH; i += 1024) {
            int r = i >> 6, c = i & 63;
            float4 k4 = *(const float4*)(Kp + kt * DH + i);
            Ks[r][c + 0] = k4.x; Ks[r][c + 1] = k4.y;
            Ks[r][c + 2] = k4.z; Ks[r][c + 3] = k4.w;
            float4 v4 = *(const float4*)(Vp + kt * DH + i);
            Vs[r][c + 0] = v4.x; Vs[r][c + 1] = v4.y;
            Vs[r][c + 2] = v4.z; Vs[r][c + 3] = v4.w;
        }
        __syncthreads();

        // scores: thread handles s = grp + 8*j, j=0..7
        float sc[8];
        #pragma unroll
        for (int j = 0; j < 8; j++) {
            int s = grp + j * 8;
            const float4* krow = (const float4*)&Ks[s][0];
            float acc = 0.f;
            #pragma unroll
            for (int d4 = 0; d4 < 16; d4++) {
                float4 k4 = krow[d4];
                acc = fmaf(q[d4].x, k4.x, acc);
                acc = fmaf(q[d4].y, k4.y, acc);
                acc = fmaf(q[d4].z, k4.z, acc);
                acc = fmaf(q[d4].w, k4.w, acc);
            }
            sc[j] = mp[kt + s] ? -1e9f : acc;
        }

        // online softmax (reduce across 8-lane row group)
        float mt = sc[0];
        #pragma unroll
        for (int j = 1; j < 8; j++) mt = fmaxf(mt, sc[j]);
        #pragma unroll
        for (int w = 1; w < 8; w <<= 1) mt = fmaxf(mt, __shfl_xor(mt, w, 8));
        float mnew = fmaxf(m, mt);
        float corr = __expf(m - mnew);
        float p[8];
        float lt = 0.f;
        #pragma unroll
        for (int j = 0; j < 8; j++) { p[j] = __expf(sc[j] - mnew); lt += p[j]; }
        #pragma unroll
        for (int w = 1; w < 8; w <<= 1) lt += __shfl_xor(lt, w, 8);
        l = l * corr + lt;
        m = mnew;

        // o = o*corr + P @ V  (broadcast p across the 8-lane row group)
        #pragma unroll
        for (int i = 0; i < 8; i++) o[i] *= corr;
        #pragma unroll
        for (int j = 0; j < 8; j++) {
            #pragma unroll
            for (int w = 0; w < 8; w++) {
                float pv = __shfl(p[j], w, 8);
                const float4* vp4 = (const float4*)&Vs[w + j * 8][grp << 3];
                float4 v0 = vp4[0], v1 = vp4[1];
                o[0] = fmaf(pv, v0.x, o[0]); o[1] = fmaf(pv, v0.y, o[1]);
                o[2] = fmaf(pv, v0.z, o[2]); o[3] = fmaf(pv, v0.w, o[3]);
                o[4] = fmaf(pv, v1.x, o[4]); o[5] = fmaf(pv, v1.y, o[5]);
                o[6] = fmaf(pv, v1.z, o[6]); o[7] = fmaf(pv, v1.w, o[7]);
            }
        }
    }

    float inv = 1.f / l;
    // write O in (B, L, E) layout so out-proj GEMM is standard row-major
    float* Op = O + ((size_t)(b * L_ + qt * QB + row)) * E_ + h * DH + (grp << 3);
    float4 r0 = make_float4(o[0] * inv, o[1] * inv, o[2] * inv, o[3] * inv);
    float4 r1 = make_float4(o[4] * inv, o[5] * inv, o[6] * inv, o[7] * inv);
    ((float4*)Op)[0] = r0;
    ((float4*)Op)[1] = r1;
}

// ---------------- host launch ----------------
extern "C" void kernel_launch(void* const* d_in, const int* in_sizes, int n_in,
                              void* d_out, int out_size, void* d_ws, size_t ws_size,
                              hipStream_t stream) {
    const float* x     = (const float*)d_in[0];
    const float* w_in  = (const float*)d_in[1];
    const float* b_in  = (const float*)d_in[2];
    const float* w_out = (const float*)d_in[3];
    const float* b_out = (const float*)d_in[4];
    const float* qs    = (const float*)d_in[5];
    const unsigned char* mask = (const unsigned char*)d_in[6];
    float* out = (float*)d_out;

    float* ws = (float*)d_ws;
    const size_t NELEM = (size_t)B_ * L_ * E_;   // 8388608 per tensor
    float* qscale = ws;            // 64 floats (padded to 64)
    float* Qw = ws + 64;           // (B*H, L, DH)
    float* Kw = Qw + NELEM;
    float* Vw = Kw + NELEM;
    float* Ow = Vw + NELEM;        // (B, L, E)

    qscale_kernel<<<1, 64, 0, stream>>>(qs, qscale);
    gemm_fp32<0><<<dim3((B_ * L_) / TM, (3 * E_) / TN), 256, 0, stream>>>(
        x, w_in, b_in, qscale, Qw, Kw, Vw);
    attn_kernel<<<dim3(L_ / QB, B_ * H_), 256, 0, stream>>>(Qw, Kw, Vw, mask, Ow);
    gemm_fp32<1><<<dim3((B_ * L_) / TM, E_ / TN), 256, 0, stream>>>(
        Ow, w_out, b_out, nullptr, out, nullptr, nullptr);
}

// Round 3
// 652.360 us; speedup vs baseline: 1.7882x; 1.7882x over previous
//
#include <hip/hip_runtime.h>
#include <hip/hip_bf16.h>
#include <math.h>

// Problem constants (fixed by setup_inputs)
#define B_ 16
#define L_ 1024
#define E_ 512
#define H_ 8
#define DH 64

typedef __attribute__((ext_vector_type(8))) short bf16x8;
typedef __attribute__((ext_vector_type(4))) float f32x4;

__device__ inline unsigned short f2b(float x) {
    __hip_bfloat16 h = __float2bfloat16(x);
    unsigned short u; __builtin_memcpy(&u, &h, 2); return u;
}

// ---------------- QueryScaler precompute ----------------
__global__ void qscale_kernel(const float* __restrict__ qs_scale,
                              float* __restrict__ qscale) {
    int d = threadIdx.x;
    if (d < DH) {
        float x = qs_scale[d];
        float sp = (x > 20.f) ? x : log1pf(expf(x));
        qscale[d] = 1.442695041f * sp * 0.125f;
    }
}

// ---------------- Tiled fp32 GEMM: C = A(M,512) * W(N,512)^T + bias --------
// MODE 0: QKV projection -> bf16 Q (scaled), bf16 K, bf16 V^T
// MODE 1: out projection -> Dout fp32
#define TM 128
#define TN 128
#define TK 16

template<int MODE>
__global__ __launch_bounds__(256) void gemm_fp32(
    const float* __restrict__ A, const float* __restrict__ W,
    const float* __restrict__ bias, const float* __restrict__ qscale,
    float* __restrict__ Dout, __hip_bfloat16* __restrict__ Qb,
    __hip_bfloat16* __restrict__ Kb, __hip_bfloat16* __restrict__ Vtb)
{
    __shared__ float As[TK][TM + 4];
    __shared__ float Bs[TK][TN + 4];
    const int tid = threadIdx.x;
    const int m0 = blockIdx.x * TM;
    const int n0 = blockIdx.y * TN;
    const int lr = tid >> 2;
    const int lc = (tid & 3) << 2;
    const int tr = (tid >> 4) << 3;
    const int tc = (tid & 15) << 3;
    float acc[8][8] = {};

    for (int k0 = 0; k0 < E_; k0 += TK) {
        #pragma unroll
        for (int hh = 0; hh < 2; hh++) {
            int r = lr + hh * 64;
            float4 av = *(const float4*)(A + (size_t)(m0 + r) * E_ + k0 + lc);
            As[lc + 0][r] = av.x; As[lc + 1][r] = av.y;
            As[lc + 2][r] = av.z; As[lc + 3][r] = av.w;
            float4 bv = *(const float4*)(W + (size_t)(n0 + r) * E_ + k0 + lc);
            Bs[lc + 0][r] = bv.x; Bs[lc + 1][r] = bv.y;
            Bs[lc + 2][r] = bv.z; Bs[lc + 3][r] = bv.w;
        }
        __syncthreads();
        #pragma unroll
        for (int kk = 0; kk < TK; kk++) {
            float4 a0 = *(const float4*)&As[kk][tr];
            float4 a1 = *(const float4*)&As[kk][tr + 4];
            float4 b0 = *(const float4*)&Bs[kk][tc];
            float4 b1 = *(const float4*)&Bs[kk][tc + 4];
            float a[8] = {a0.x, a0.y, a0.z, a0.w, a1.x, a1.y, a1.z, a1.w};
            float b[8] = {b0.x, b0.y, b0.z, b0.w, b1.x, b1.y, b1.z, b1.w};
            #pragma unroll
            for (int i = 0; i < 8; i++)
                #pragma unroll
                for (int j = 0; j < 8; j++)
                    acc[i][j] = fmaf(a[i], b[j], acc[i][j]);
        }
        __syncthreads();
    }

    #pragma unroll
    for (int i = 0; i < 8; i++) {
        int r = m0 + tr + i;
        #pragma unroll
        for (int j = 0; j < 8; j++) {
            int f = n0 + tc + j;
            float v = acc[i][j] + bias[f];
            if (MODE == 0) {
                int bb = r >> 10;
                int l = r & (L_ - 1);
                int part = f >> 9;
                int w = f & 511;
                int h = w >> 6, d = w & 63;
                size_t bh = (size_t)(bb * H_ + h);
                if (part == 0)
                    Qb[(bh * L_ + l) * DH + d] = __float2bfloat16(v * qscale[d]);
                else if (part == 1)
                    Kb[(bh * L_ + l) * DH + d] = __float2bfloat16(v);
                else
                    Vtb[(bh * DH + d) * L_ + l] = __float2bfloat16(v);
            } else {
                Dout[(size_t)r * E_ + f] = v;
            }
        }
    }
}

// ---------------- MFMA flash attention ----------------
// One block = one wave = one (bh, 16-row Q tile). Swapped QK^T (S^T = K@Q^T),
// online softmax per q-column, P redistributed via tiny LDS tile, PV with V^T.
// NOTE: softmax state lives in "column space" (q = lane&15); the PV
// accumulator lives in "row space" (q = (lane>>4)*4+reg). Every per-tile
// rescale of oacc must remap corr through __shfl(corr, 4g+r). (Round-2 bug.)
__global__ __launch_bounds__(64) void attn_mfma(
    const __hip_bfloat16* __restrict__ Q, const __hip_bfloat16* __restrict__ K,
    const __hip_bfloat16* __restrict__ Vt, const unsigned char* __restrict__ mask,
    float* __restrict__ O)
{
    __shared__ unsigned short P_lds[16][40];   // 32 keys + pad

    // XCD-bijective swizzle: 64 Q-tiles of one bh land on one XCD
    const int bid = blockIdx.x;                // 0..8191
    const int w = (bid & 7) * 1024 + (bid >> 3);
    const int bh = w >> 6;                     // 0..127
    const int qt = w & 63;                     // 0..63
    const int b = bh >> 3;
    const int h = bh & (H_ - 1);

    const int lane = threadIdx.x;
    const int g = lane >> 4;                   // 0..3
    const int c = lane & 15;                   // 0..15

    const __hip_bfloat16* Qp = Q + ((size_t)bh * L_ + qt * 16) * DH;
    const __hip_bfloat16* Kp = K + (size_t)bh * L_ * DH;
    const __hip_bfloat16* Vp = Vt + (size_t)bh * DH * L_;
    const unsigned char* mp = mask + (size_t)b * L_;

    // Q B-fragments: lane holds Q[q0+c][g*8+j], d-chunks 0 and 32
    bf16x8 qf0 = *(const bf16x8*)(Qp + c * DH + g * 8);
    bf16x8 qf1 = *(const bf16x8*)(Qp + c * DH + 32 + g * 8);

    f32x4 oacc[4];
    #pragma unroll
    for (int i = 0; i < 4; i++) oacc[i] = (f32x4){0.f, 0.f, 0.f, 0.f};
    float mrun = -INFINITY, lrun = 0.f;

    for (int kt = 0; kt < L_; kt += 32) {
        // K A-fragments: lane = K[kt+c (+16)][dchunk + g*8+j]
        const __hip_bfloat16* kp0 = Kp + (size_t)(kt + c) * DH + g * 8;
        bf16x8 k00 = *(const bf16x8*)(kp0);
        bf16x8 k01 = *(const bf16x8*)(kp0 + 32);
        bf16x8 k10 = *(const bf16x8*)(kp0 + 16 * DH);
        bf16x8 k11 = *(const bf16x8*)(kp0 + 16 * DH + 32);
        // V B-fragments for PV (issued early; held across softmax)
        bf16x8 vb[4];
        #pragma unroll
        for (int dc = 0; dc < 4; dc++)
            vb[dc] = *(const bf16x8*)(Vp + (size_t)(dc * 16 + c) * L_ + kt + g * 8);

        f32x4 st0 = {0.f, 0.f, 0.f, 0.f}, st1 = {0.f, 0.f, 0.f, 0.f};
        st0 = __builtin_amdgcn_mfma_f32_16x16x32_bf16(k00, qf0, st0, 0, 0, 0);
        st0 = __builtin_amdgcn_mfma_f32_16x16x32_bf16(k01, qf1, st0, 0, 0, 0);
        st1 = __builtin_amdgcn_mfma_f32_16x16x32_bf16(k10, qf0, st1, 0, 0, 0);
        st1 = __builtin_amdgcn_mfma_f32_16x16x32_bf16(k11, qf1, st1, 0, 0, 0);
        // lane: S^T[key = kt+4g+r (st0) / kt+16+4g+r (st1)][q = q0+c]

        unsigned char mb = mp[kt + (lane & 31)];
        if (__ballot(mb != 0)) {
            #pragma unroll
            for (int r = 0; r < 4; r++) {
                if (mp[kt + 4 * g + r])      st0[r] = -1e9f;
                if (mp[kt + 16 + 4 * g + r]) st1[r] = -1e9f;
            }
        }

        // online softmax over this 32-key tile (per q = column c)
        float tm = fmaxf(fmaxf(fmaxf(st0[0], st0[1]), fmaxf(st0[2], st0[3])),
                         fmaxf(fmaxf(st1[0], st1[1]), fmaxf(st1[2], st1[3])));
        tm = fmaxf(tm, __shfl_xor(tm, 16));
        tm = fmaxf(tm, __shfl_xor(tm, 32));
        float mnew = fmaxf(mrun, tm);
        float corr = __expf(mrun - mnew);          // corr for q = c

        float p0[4], p1[4];
        float ls = 0.f;
        #pragma unroll
        for (int r = 0; r < 4; r++) {
            p0[r] = __expf(st0[r] - mnew);
            p1[r] = __expf(st1[r] - mnew);
            ls += p0[r] + p1[r];
        }
        ls += __shfl_xor(ls, 16);
        ls += __shfl_xor(ls, 32);
        lrun = lrun * corr + ls;
        mrun = mnew;

        // remap corr from column space (q=c) to row space (q=4g+r), then rescale
        float corr_row[4];
        #pragma unroll
        for (int r = 0; r < 4; r++) corr_row[r] = __shfl(corr, 4 * g + r);
        #pragma unroll
        for (int dc = 0; dc < 4; dc++) {
            #pragma unroll
            for (int r = 0; r < 4; r++) oacc[dc][r] *= corr_row[r];
        }

        // P^T -> LDS in [q][key] layout (bf16), then read A-fragments
        ushort4 pk0, pk1;
        pk0.x = f2b(p0[0]); pk0.y = f2b(p0[1]); pk0.z = f2b(p0[2]); pk0.w = f2b(p0[3]);
        pk1.x = f2b(p1[0]); pk1.y = f2b(p1[1]); pk1.z = f2b(p1[2]); pk1.w = f2b(p1[3]);
        *(ushort4*)(&P_lds[c][4 * g]) = pk0;
        *(ushort4*)(&P_lds[c][16 + 4 * g]) = pk1;
        __syncthreads();
        bf16x8 pf = *(const bf16x8*)(&P_lds[c][g * 8]);   // A: row=q=c, key=g*8+j
        __syncthreads();

        #pragma unroll
        for (int dc = 0; dc < 4; dc++)
            oacc[dc] = __builtin_amdgcn_mfma_f32_16x16x32_bf16(pf, vb[dc], oacc[dc], 0, 0, 0);
        // oacc[dc]: lane holds O[q = 4g+r][d = dc*16+c]
    }

    // normalize (row-space l fetched via shfl) and write O in (B, L, E) fp32
    float linv[4];
    #pragma unroll
    for (int r = 0; r < 4; r++) {
        float lq = __shfl(lrun, 4 * g + r);
        linv[r] = 1.f / lq;
    }
    #pragma unroll
    for (int dc = 0; dc < 4; dc++) {
        #pragma unroll
        for (int r = 0; r < 4; r++) {
            int qrow = qt * 16 + 4 * g + r;
            O[((size_t)(b * L_ + qrow)) * E_ + h * DH + dc * 16 + c] = oacc[dc][r] * linv[r];
        }
    }
}

// ---------------- host launch ----------------
extern "C" void kernel_launch(void* const* d_in, const int* in_sizes, int n_in,
                              void* d_out, int out_size, void* d_ws, size_t ws_size,
                              hipStream_t stream) {
    const float* x     = (const float*)d_in[0];
    const float* w_in  = (const float*)d_in[1];
    const float* b_in  = (const float*)d_in[2];
    const float* w_out = (const float*)d_in[3];
    const float* b_out = (const float*)d_in[4];
    const float* qs    = (const float*)d_in[5];
    const unsigned char* mask = (const unsigned char*)d_in[6];
    float* out = (float*)d_out;

    float* ws = (float*)d_ws;
    const size_t NELEM = (size_t)B_ * L_ * E_;   // 8388608
    float* qscale = ws;                          // 64 floats
    float* Ow = ws + 64;                         // (B, L, E) fp32
    __hip_bfloat16* Qb  = (__hip_bfloat16*)(Ow + NELEM);
    __hip_bfloat16* Kb  = Qb + NELEM;
    __hip_bfloat16* Vtb = Kb + NELEM;

    qscale_kernel<<<1, 64, 0, stream>>>(qs, qscale);
    gemm_fp32<0><<<dim3((B_ * L_) / TM, (3 * E_) / TN), 256, 0, stream>>>(
        x, w_in, b_in, qscale, nullptr, Qb, Kb, Vtb);
    attn_mfma<<<dim3((L_ / 16) * (B_ * H_)), 64, 0, stream>>>(Qb, Kb, Vtb, mask, Ow);
    gemm_fp32<1><<<dim3((B_ * L_) / TM, E_ / TN), 256, 0, stream>>>(
        Ow, w_out, b_out, nullptr, out, nullptr, nullptr, nullptr);
}

// Round 4
// 301.496 us; speedup vs baseline: 3.8692x; 2.1637x over previous
//
#include <hip/hip_runtime.h>
#include <hip/hip_bf16.h>
#include <math.h>

// Problem constants (fixed by setup_inputs)
#define B_ 16
#define L_ 1024
#define E_ 512
#define H_ 8
#define DH 64

typedef unsigned short u16;
typedef __attribute__((ext_vector_type(8))) short bf16x8;
typedef __attribute__((ext_vector_type(8))) unsigned short u16x8;
typedef __attribute__((ext_vector_type(4))) float f32x4;

__device__ inline u16 f2b(float x) {
    __hip_bfloat16 h = __float2bfloat16(x);
    u16 u; __builtin_memcpy(&u, &h, 2); return u;
}

// ---------------- QueryScaler precompute ----------------
__global__ void qscale_kernel(const float* __restrict__ qs_scale,
                              float* __restrict__ qscale) {
    int d = threadIdx.x;
    if (d < DH) {
        float x = qs_scale[d];
        float sp = (x > 20.f) ? x : log1pf(expf(x));
        qscale[d] = 1.442695041f * sp * 0.125f;
    }
}

// ---------------- fp32 -> bf16 conversion (x, w_in, w_out) ----------------
// chunk regions (in units of 8 elems): x: [0,1048576) wi: [...,1146880) wo: [...,1179648)
__global__ __launch_bounds__(256) void cvt_bf16(
    const float* __restrict__ x, const float* __restrict__ wi,
    const float* __restrict__ wo, u16* __restrict__ xb,
    u16* __restrict__ wib, u16* __restrict__ wob)
{
    int i = blockIdx.x * 256 + threadIdx.x;
    const float* src; u16* dst; size_t off;
    if (i < 1048576)      { src = x;  dst = xb;  off = (size_t)i * 8; }
    else if (i < 1146880) { src = wi; dst = wib; off = (size_t)(i - 1048576) * 8; }
    else                  { src = wo; dst = wob; off = (size_t)(i - 1146880) * 8; }
    float4 a = *(const float4*)(src + off);
    float4 b = *(const float4*)(src + off + 4);
    u16x8 r;
    r[0] = f2b(a.x); r[1] = f2b(a.y); r[2] = f2b(a.z); r[3] = f2b(a.w);
    r[4] = f2b(b.x); r[5] = f2b(b.y); r[6] = f2b(b.z); r[7] = f2b(b.w);
    *(u16x8*)(dst + off) = r;
}

// ---------------- bf16 MFMA GEMM: C = A(M,512) @ W(N,512)^T + bias --------
// 128x128 tile, BK=32, 4 waves (2x2), each wave 4x4 16x16x32 fragments.
// LDS rows padded to 36 u16 (72B) to break stride-64B read conflicts.
// MODE 0: QKV -> bf16 Q(scaled)/K row-major, V^T (ushort4 l-contiguous)
// MODE 1: out-projection -> fp32 Dout + bias
template<int MODE>
__global__ __launch_bounds__(256) void gemm_bf16(
    const u16* __restrict__ A, const u16* __restrict__ W,
    const float* __restrict__ bias, const float* __restrict__ qscale,
    float* __restrict__ Dout, u16* __restrict__ Qb, u16* __restrict__ Kb,
    u16* __restrict__ Vtb)
{
    __shared__ u16 sA[128][36];
    __shared__ u16 sB[128][36];
    const int tid = threadIdx.x;
    const int m0 = blockIdx.x * 128;
    const int n0 = blockIdx.y * 128;
    const int wid = tid >> 6, lane = tid & 63;
    const int g = lane >> 4, c = lane & 15;
    const int wr = wid >> 1, wc = wid & 1;

    // staging map: thread covers rows srow, srow+64 at 16B slot sslot
    const int srow = tid >> 2;
    const int sslot = tid & 3;
    const u16* Ap = A + (size_t)(m0 + srow) * 512 + sslot * 8;
    const u16* Wp = W + (size_t)(n0 + srow) * 512 + sslot * 8;

    f32x4 acc[4][4];
    #pragma unroll
    for (int m = 0; m < 4; m++)
        #pragma unroll
        for (int n = 0; n < 4; n++) acc[m][n] = (f32x4){0.f, 0.f, 0.f, 0.f};

    // prefetch K-step 0 into registers
    bf16x8 ra0 = *(const bf16x8*)(Ap);
    bf16x8 ra1 = *(const bf16x8*)(Ap + (size_t)64 * 512);
    bf16x8 rb0 = *(const bf16x8*)(Wp);
    bf16x8 rb1 = *(const bf16x8*)(Wp + (size_t)64 * 512);

    #pragma unroll 1
    for (int ks = 0; ks < 16; ks++) {
        __syncthreads();
        *(bf16x8*)&sA[srow][sslot * 8] = ra0;
        *(bf16x8*)&sA[srow + 64][sslot * 8] = ra1;
        *(bf16x8*)&sB[srow][sslot * 8] = rb0;
        *(bf16x8*)&sB[srow + 64][sslot * 8] = rb1;
        __syncthreads();
        if (ks < 15) {
            int k0 = (ks + 1) * 32;
            ra0 = *(const bf16x8*)(Ap + k0);
            ra1 = *(const bf16x8*)(Ap + (size_t)64 * 512 + k0);
            rb0 = *(const bf16x8*)(Wp + k0);
            rb1 = *(const bf16x8*)(Wp + (size_t)64 * 512 + k0);
        }
        bf16x8 af[4], bfr[4];
        #pragma unroll
        for (int m = 0; m < 4; m++)
            af[m] = *(const bf16x8*)&sA[wr * 64 + m * 16 + c][g * 8];
        #pragma unroll
        for (int n = 0; n < 4; n++)
            bfr[n] = *(const bf16x8*)&sB[wc * 64 + n * 16 + c][g * 8];
        #pragma unroll
        for (int m = 0; m < 4; m++)
            #pragma unroll
            for (int n = 0; n < 4; n++)
                acc[m][n] = __builtin_amdgcn_mfma_f32_16x16x32_bf16(af[m], bfr[n], acc[m][n], 0, 0, 0);
    }

    // epilogue: C[row = m0+wr*64+m*16+4g+reg][col = n0+wc*64+n*16+c]
    #pragma unroll
    for (int m = 0; m < 4; m++) {
        int rbase = m0 + wr * 64 + m * 16 + 4 * g;
        #pragma unroll
        for (int n = 0; n < 4; n++) {
            int f = n0 + wc * 64 + n * 16 + c;
            f32x4 v = acc[m][n];
            float bv = bias[f];
            if (MODE == 1) {
                #pragma unroll
                for (int reg = 0; reg < 4; reg++)
                    Dout[(size_t)(rbase + reg) * E_ + f] = v[reg] + bv;
            } else {
                int part = f >> 9, w = f & 511, h = w >> 6, d = w & 63;
                int bb = rbase >> 10;
                int l0 = rbase & 1023;
                size_t bh = (size_t)(bb * H_ + h);
                if (part == 0) {
                    float qs = qscale[d];
                    #pragma unroll
                    for (int reg = 0; reg < 4; reg++)
                        Qb[(bh * L_ + l0 + reg) * DH + d] = f2b((v[reg] + bv) * qs);
                } else if (part == 1) {
                    #pragma unroll
                    for (int reg = 0; reg < 4; reg++)
                        Kb[(bh * L_ + l0 + reg) * DH + d] = f2b(v[reg] + bv);
                } else {
                    ushort4 pk;
                    pk.x = f2b(v[0] + bv); pk.y = f2b(v[1] + bv);
                    pk.z = f2b(v[2] + bv); pk.w = f2b(v[3] + bv);
                    *(ushort4*)(Vtb + (bh * DH + d) * L_ + l0) = pk;
                }
            }
        }
    }
}

// ---------------- MFMA flash attention ----------------
// One block = one wave = one (bh, 16-row Q tile). Swapped QK^T (S^T = K@Q^T),
// online softmax per q-column, P redistributed via tiny LDS tile, PV with V^T.
// Softmax state is column-space (q = lane&15); PV accumulator is row-space
// (q = 4g+reg) -> per-tile corr must be remapped via __shfl(corr, 4g+r).
__global__ __launch_bounds__(64) void attn_mfma(
    const u16* __restrict__ Q, const u16* __restrict__ K,
    const u16* __restrict__ Vt, const unsigned char* __restrict__ mask,
    u16* __restrict__ O)
{
    __shared__ u16 P_lds[16][40];

    const int bid = blockIdx.x;                // 0..8191
    const int w = (bid & 7) * 1024 + (bid >> 3);
    const int bh = w >> 6;
    const int qt = w & 63;
    const int b = bh >> 3;
    const int h = bh & (H_ - 1);

    const int lane = threadIdx.x;
    const int g = lane >> 4;
    const int c = lane & 15;

    const u16* Qp = Q + ((size_t)bh * L_ + qt * 16) * DH;
    const u16* Kp = K + (size_t)bh * L_ * DH;
    const u16* Vp = Vt + (size_t)bh * DH * L_;
    const unsigned char* mp = mask + (size_t)b * L_;

    bf16x8 qf0 = *(const bf16x8*)(Qp + c * DH + g * 8);
    bf16x8 qf1 = *(const bf16x8*)(Qp + c * DH + 32 + g * 8);

    f32x4 oacc[4];
    #pragma unroll
    for (int i = 0; i < 4; i++) oacc[i] = (f32x4){0.f, 0.f, 0.f, 0.f};
    float mrun = -INFINITY, lrun = 0.f;

    for (int kt = 0; kt < L_; kt += 32) {
        const u16* kp0 = Kp + (size_t)(kt + c) * DH + g * 8;
        bf16x8 k00 = *(const bf16x8*)(kp0);
        bf16x8 k01 = *(const bf16x8*)(kp0 + 32);
        bf16x8 k10 = *(const bf16x8*)(kp0 + 16 * DH);
        bf16x8 k11 = *(const bf16x8*)(kp0 + 16 * DH + 32);
        bf16x8 vb[4];
        #pragma unroll
        for (int dc = 0; dc < 4; dc++)
            vb[dc] = *(const bf16x8*)(Vp + (size_t)(dc * 16 + c) * L_ + kt + g * 8);

        f32x4 st0 = {0.f, 0.f, 0.f, 0.f}, st1 = {0.f, 0.f, 0.f, 0.f};
        st0 = __builtin_amdgcn_mfma_f32_16x16x32_bf16(k00, qf0, st0, 0, 0, 0);
        st0 = __builtin_amdgcn_mfma_f32_16x16x32_bf16(k01, qf1, st0, 0, 0, 0);
        st1 = __builtin_amdgcn_mfma_f32_16x16x32_bf16(k10, qf0, st1, 0, 0, 0);
        st1 = __builtin_amdgcn_mfma_f32_16x16x32_bf16(k11, qf1, st1, 0, 0, 0);
        // lane: S^T[key = kt+4g+r (st0) / kt+16+4g+r (st1)][q = q0+c]

        unsigned char mb = mp[kt + (lane & 31)];
        if (__ballot(mb != 0)) {
            #pragma unroll
            for (int r = 0; r < 4; r++) {
                if (mp[kt + 4 * g + r])      st0[r] = -1e9f;
                if (mp[kt + 16 + 4 * g + r]) st1[r] = -1e9f;
            }
        }

        float tm = fmaxf(fmaxf(fmaxf(st0[0], st0[1]), fmaxf(st0[2], st0[3])),
                         fmaxf(fmaxf(st1[0], st1[1]), fmaxf(st1[2], st1[3])));
        tm = fmaxf(tm, __shfl_xor(tm, 16));
        tm = fmaxf(tm, __shfl_xor(tm, 32));
        float mnew = fmaxf(mrun, tm);
        float corr = __expf(mrun - mnew);          // corr for q = c

        float p0[4], p1[4];
        float ls = 0.f;
        #pragma unroll
        for (int r = 0; r < 4; r++) {
            p0[r] = __expf(st0[r] - mnew);
            p1[r] = __expf(st1[r] - mnew);
            ls += p0[r] + p1[r];
        }
        ls += __shfl_xor(ls, 16);
        ls += __shfl_xor(ls, 32);
        lrun = lrun * corr + ls;
        mrun = mnew;

        float corr_row[4];
        #pragma unroll
        for (int r = 0; r < 4; r++) corr_row[r] = __shfl(corr, 4 * g + r);
        #pragma unroll
        for (int dc = 0; dc < 4; dc++) {
            #pragma unroll
            for (int r = 0; r < 4; r++) oacc[dc][r] *= corr_row[r];
        }

        ushort4 pk0, pk1;
        pk0.x = f2b(p0[0]); pk0.y = f2b(p0[1]); pk0.z = f2b(p0[2]); pk0.w = f2b(p0[3]);
        pk1.x = f2b(p1[0]); pk1.y = f2b(p1[1]); pk1.z = f2b(p1[2]); pk1.w = f2b(p1[3]);
        *(ushort4*)(&P_lds[c][4 * g]) = pk0;
        *(ushort4*)(&P_lds[c][16 + 4 * g]) = pk1;
        __syncthreads();
        bf16x8 pf = *(const bf16x8*)(&P_lds[c][g * 8]);
        __syncthreads();

        #pragma unroll
        for (int dc = 0; dc < 4; dc++)
            oacc[dc] = __builtin_amdgcn_mfma_f32_16x16x32_bf16(pf, vb[dc], oacc[dc], 0, 0, 0);
    }

    float linv[4];
    #pragma unroll
    for (int r = 0; r < 4; r++) {
        float lq = __shfl(lrun, 4 * g + r);
        linv[r] = 1.f / lq;
    }
    #pragma unroll
    for (int dc = 0; dc < 4; dc++) {
        #pragma unroll
        for (int r = 0; r < 4; r++) {
            int qrow = qt * 16 + 4 * g + r;
            O[((size_t)(b * L_ + qrow)) * E_ + h * DH + dc * 16 + c] =
                f2b(oacc[dc][r] * linv[r]);
        }
    }
}

// ---------------- host launch ----------------
extern "C" void kernel_launch(void* const* d_in, const int* in_sizes, int n_in,
                              void* d_out, int out_size, void* d_ws, size_t ws_size,
                              hipStream_t stream) {
    const float* x     = (const float*)d_in[0];
    const float* w_in  = (const float*)d_in[1];
    const float* b_in  = (const float*)d_in[2];
    const float* w_out = (const float*)d_in[3];
    const float* b_out = (const float*)d_in[4];
    const float* qs    = (const float*)d_in[5];
    const unsigned char* mask = (const unsigned char*)d_in[6];
    float* out = (float*)d_out;

    char* base = (char*)d_ws;
    const size_t NELEM = (size_t)B_ * L_ * E_;   // 8388608
    float* qscale = (float*)base;                // 256 B
    u16* xb  = (u16*)(base + 256);
    u16* wib = xb + NELEM;                       // 786432
    u16* wob = wib + 786432;                     // 262144
    u16* Qb  = wob + 262144;
    u16* Kb  = Qb + NELEM;
    u16* Vtb = Kb + NELEM;
    u16* Ob  = Vtb + NELEM;

    qscale_kernel<<<1, 64, 0, stream>>>(qs, qscale);
    cvt_bf16<<<4608, 256, 0, stream>>>(x, w_in, w_out, xb, wib, wob);
    gemm_bf16<0><<<dim3(128, 12), 256, 0, stream>>>(
        xb, wib, b_in, qscale, nullptr, Qb, Kb, Vtb);
    attn_mfma<<<dim3((L_ / 16) * (B_ * H_)), 64, 0, stream>>>(Qb, Kb, Vtb, mask, Ob);
    gemm_bf16<1><<<dim3(128, 4), 256, 0, stream>>>(
        Ob, wob, b_out, nullptr, out, nullptr, nullptr, nullptr);
}